// Round 5
// baseline (197.517 us; speedup 1.0000x reference)
//
#include <hip/hip_runtime.h>

#define NT 64
#define NB 8192
#define NS 32
#define NF 16
#define DT 0.05f
#define FP_ITERS 4
#define YSTR 36   // floats per batch row in Y LDS (32 + 4 pad)

typedef float f32x2 __attribute__((ext_vector_type(2)));
typedef float f32x4 __attribute__((ext_vector_type(4)));

// tanh(x) = 1 - 2/(1 + exp2(K x)), K = 2 log2 e.  v_exp_f32/v_rcp_f32 raw.
__device__ __forceinline__ f32x2 tanh2(f32x2 x) {
    const float K = 2.8853900817779268f;
    float e0 = __builtin_amdgcn_exp2f(K * x[0]);
    float e1 = __builtin_amdgcn_exp2f(K * x[1]);
    float r0 = __builtin_amdgcn_rcpf(e0 + 1.0f);
    float r1 = __builtin_amdgcn_rcpf(e1 + 1.0f);
    f32x2 r;
    r[0] = fmaf(-2.0f, r0, 1.0f);
    r[1] = fmaf(-2.0f, r1, 1.0f);
    return r;
}

// Lane map: lane = b*16 + p; b in [0,4) selects batch-within-set, p in [0,16)
// selects the state pair (states 2p, 2p+1). Each wave owns TWO sets of 4
// batches (8 batches total) whose solver chains are statically interleaved
// for ILP — the wave is alone on its SIMD (1024 waves / 1024 SIMDs).
// Intra-wave lockstep + in-order DS pipe make the y-exchange barrier-free
// (validated R2-R4).
__global__ __launch_bounds__(256, 1) void rnes_kernel(
    const float* __restrict__ y0,
    const float* __restrict__ forces,
    const float* __restrict__ W,
    const float* __restrict__ U,
    const float* __restrict__ bias,
    float* __restrict__ out)
{
    const int lane = threadIdx.x & 63;
    const int wv   = threadIdx.x >> 6;
    const int b    = lane >> 4;
    const int p    = lane & 15;
    const int wid  = blockIdx.x * 4 + wv;

    int batch[2];
    batch[0] = wid * 8 + b;
    batch[1] = wid * 8 + 4 + b;

    __shared__ __align__(16) float Ysh[4][2][4 * YSTR];
    float* Yw[2] = { &Ysh[wv][0][b * YSTR], &Ysh[wv][1][b * YSTR] };

    // W2[k] = (W[2p][k], W[2p+1][k]) — 64 VGPRs, shared by both sets
    f32x2 W2[NS];
#pragma unroll
    for (int k = 0; k < NS; k += 4) {
        f32x4 r0 = *(const f32x4*)(W + (2*p)   * NS + k);
        f32x4 r1 = *(const f32x4*)(W + (2*p+1) * NS + k);
#pragma unroll
        for (int e = 0; e < 4; ++e) W2[k+e] = (f32x2){r0[e], r1[e]};
    }
    // U2[f] = (U[2p][f], U[2p+1][f]) — 32 VGPRs, shared by both sets
    f32x2 U2[NF];
#pragma unroll
    for (int f = 0; f < NF; f += 4) {
        f32x4 r0 = *(const f32x4*)(U + (2*p)   * NF + f);
        f32x4 r1 = *(const f32x4*)(U + (2*p+1) * NF + f);
#pragma unroll
        for (int e = 0; e < 4; ++e) U2[f+e] = (f32x2){r0[e], r1[e]};
    }
    const f32x2 b2 = *(const f32x2*)(bias + 2*p);

    // y_prev, out[0] = y0, seed Y LDS
    f32x2 yp[2];
#pragma unroll
    for (int s = 0; s < 2; ++s) {
        yp[s] = *(const f32x2*)(y0 + (size_t)batch[s] * NS + 2*p);
        *(f32x2*)(out + (size_t)batch[s] * NS + 2*p) = yp[s];
        *(f32x2*)(Yw[s] + 2*p) = yp[s];
    }
    asm volatile("" ::: "memory");

    // register prefetch of forces[1] (broadcast float4 x4 per set, no LDS)
    const size_t fstep = (size_t)NB * NF;
    f32x4 upf[2][4];
#pragma unroll
    for (int s = 0; s < 2; ++s) {
        const f32x4* fp = (const f32x4*)(forces + fstep + (size_t)batch[s] * NF);
#pragma unroll
        for (int j = 0; j < 4; ++j) upf[s][j] = fp[j];
    }

    for (int k = 1; k < NT; ++k) {
        // fu = U u + b from prefetched registers (16 pk_fma per set)
        f32x2 fu[2];
#pragma unroll
        for (int s = 0; s < 2; ++s) {
            f32x2 a0 = b2, a1 = (f32x2){0.f, 0.f};
#pragma unroll
            for (int f = 0; f < NF; f += 4) {
                f32x4 u4 = upf[s][f >> 2];
                a0 = U2[f+0] * u4[0] + a0;
                a1 = U2[f+1] * u4[1] + a1;
                a0 = U2[f+2] * u4[2] + a0;
                a1 = U2[f+3] * u4[3] + a1;
            }
            fu[s] = a0 + a1;
        }

        // prefetch next step's forces (consumed one full step later)
        {
            int kn = (k + 1 < NT) ? (k + 1) : (NT - 1);
#pragma unroll
            for (int s = 0; s < 2; ++s) {
                const f32x4* fp = (const f32x4*)(forces + (size_t)kn * fstep
                                                 + (size_t)batch[s] * NF);
#pragma unroll
                for (int j = 0; j < 4; ++j) upf[s][j] = fp[j];
            }
        }

        // fixed-point iterations, warm start y = y_prev (Y LDS already holds it)
        f32x2 y[2] = { yp[0], yp[1] };
#pragma unroll
        for (int it = 0; it < FP_ITERS; ++it) {
            f32x2 z0[2], z1[2];
#pragma unroll
            for (int s = 0; s < 2; ++s) { z0[s] = fu[s]; z1[s] = (f32x2){0.f, 0.f}; }
#pragma unroll
            for (int s = 0; s < 2; ++s) {
#pragma unroll
                for (int i = 0; i < 8; ++i) {
                    f32x4 yv = ((const f32x4*)Yw[s])[i];   // broadcast in b-group
                    z0[s] = W2[4*i+0] * yv[0] + z0[s];
                    z1[s] = W2[4*i+1] * yv[1] + z1[s];
                    z0[s] = W2[4*i+2] * yv[2] + z0[s];
                    z1[s] = W2[4*i+3] * yv[3] + z1[s];
                }
            }
#pragma unroll
            for (int s = 0; s < 2; ++s) {
                f32x2 t = tanh2(z0[s] + z1[s]);
                y[s][0] = fmaf(DT, t[0], yp[s][0]);
                y[s][1] = fmaf(DT, t[1], yp[s][1]);
            }
            // wave-lockstep: all reads above issued before these writes; DS
            // pipe is in-order per wave; clobbers pin compiler ordering.
            asm volatile("" ::: "memory");
#pragma unroll
            for (int s = 0; s < 2; ++s) *(f32x2*)(Yw[s] + 2*p) = y[s];
            asm volatile("" ::: "memory");
        }

#pragma unroll
        for (int s = 0; s < 2; ++s) {
            yp[s] = y[s];
            *(f32x2*)(out + ((size_t)k * NB + batch[s]) * NS + 2*p) = y[s];
        }
    }
}

extern "C" void kernel_launch(void* const* d_in, const int* in_sizes, int n_in,
                              void* d_out, int out_size, void* d_ws, size_t ws_size,
                              hipStream_t stream) {
    const float* y0     = (const float*)d_in[0];
    const float* forces = (const float*)d_in[1];
    const float* W      = (const float*)d_in[2];
    const float* U      = (const float*)d_in[3];
    const float* b      = (const float*)d_in[4];
    float* out = (float*)d_out;

    dim3 grid(NB / 32);   // 256 blocks x 4 waves x 8 batches = 8192
    dim3 block(256);
    rnes_kernel<<<grid, block, 0, stream>>>(y0, forces, W, U, b, out);
}

// Round 6
// 160.435 us; speedup vs baseline: 1.2311x; 1.2311x over previous
//
#include <hip/hip_runtime.h>

#define NT 64
#define NB 8192
#define NS 32
#define NF 16
#define DT 0.05f
#define FP_ITERS 3
#define YSTR 36   // floats per batch row in Y LDS (32 + 4 pad); rows land on
                  // rotated bank offsets (36 mod 32 = 4) -> b128 reads conflict-free

typedef float f32x2 __attribute__((ext_vector_type(2)));
typedef float f32x4 __attribute__((ext_vector_type(4)));

// tanh(x) = 1 - 2/(1 + exp2(K x)), K = 2*log2(e). 6 VALU ops per pair.
__device__ __forceinline__ f32x2 tanh2(f32x2 x) {
    const float K = 2.8853900817779268f;
    float e0 = __builtin_amdgcn_exp2f(K * x[0]);
    float e1 = __builtin_amdgcn_exp2f(K * x[1]);
    float r0 = __builtin_amdgcn_rcpf(e0 + 1.0f);
    float r1 = __builtin_amdgcn_rcpf(e1 + 1.0f);
    f32x2 r;
    r[0] = fmaf(-2.0f, r0, 1.0f);
    r[1] = fmaf(-2.0f, r1, 1.0f);
    return r;
}

// Lane map: lane = b*16 + p; b in [0,4) = batch within wave, p in [0,16) =
// state pair (states 2p,2p+1). 4 batches/wave -> 2048 waves = 2/SIMD (R4's
// best-measured TLP). y-exchange stays intra-wave: lockstep + in-order DS
// pipe make it barrier-free (validated R2-R5).
__global__ __launch_bounds__(256, 2) void rnes_kernel(
    const float* __restrict__ y0,
    const float* __restrict__ forces,
    const float* __restrict__ W,
    const float* __restrict__ U,
    const float* __restrict__ bias,
    float* __restrict__ out)
{
    const int lane = threadIdx.x & 63;
    const int wv   = threadIdx.x >> 6;
    const int b    = lane >> 4;
    const int p    = lane & 15;
    const int batch = blockIdx.x * 16 + wv * 4 + b;

    __shared__ __align__(16) float Ysh[4][4 * YSTR];
    float* Yw = Ysh[wv] + b * YSTR;

    // W2[k] = (W[2p][k], W[2p+1][k]) — 64 VGPRs
    f32x2 W2[NS];
#pragma unroll
    for (int k = 0; k < NS; k += 4) {
        f32x4 r0 = *(const f32x4*)(W + (2*p)   * NS + k);
        f32x4 r1 = *(const f32x4*)(W + (2*p+1) * NS + k);
#pragma unroll
        for (int e = 0; e < 4; ++e) W2[k+e] = (f32x2){r0[e], r1[e]};
    }
    // U2[f] = (U[2p][f], U[2p+1][f]) — 32 VGPRs
    f32x2 U2[NF];
#pragma unroll
    for (int f = 0; f < NF; f += 4) {
        f32x4 r0 = *(const f32x4*)(U + (2*p)   * NF + f);
        f32x4 r1 = *(const f32x4*)(U + (2*p+1) * NF + f);
#pragma unroll
        for (int e = 0; e < 4; ++e) U2[f+e] = (f32x2){r0[e], r1[e]};
    }
    const f32x2 b2 = *(const f32x2*)(bias + 2*p);

    // y_prev, out[0] = y0, seed Y LDS with warm start
    f32x2 yp = *(const f32x2*)(y0 + (size_t)batch * NS + 2*p);
    *(f32x2*)(out + (size_t)batch * NS + 2*p) = yp;
    *(f32x2*)(Yw + 2*p) = yp;
    asm volatile("" ::: "memory");

    // register prefetch of forces[1]: broadcast f32x4 x4 per b-group (no LDS)
    const size_t fstep = (size_t)NB * NF;
    const f32x4* fb = (const f32x4*)(forces + (size_t)batch * NF);
    f32x4 upf[4];
#pragma unroll
    for (int j = 0; j < 4; ++j) upf[j] = fb[(fstep >> 2) + j];

    for (int k = 1; k < NT; ++k) {
        // fu = U u + b from prefetched registers (2 accumulators)
        f32x2 a0 = b2, a1 = (f32x2){0.f, 0.f};
#pragma unroll
        for (int f = 0; f < NF; f += 4) {
            f32x4 u4 = upf[f >> 2];
            a0 = U2[f+0] * u4[0] + a0;
            a1 = U2[f+1] * u4[1] + a1;
            a0 = U2[f+2] * u4[2] + a0;
            a1 = U2[f+3] * u4[3] + a1;
        }
        const f32x2 fu = a0 + a1;

        // prefetch next step's forces (in flight across all 3 iterations)
        {
            int kn = (k + 1 < NT) ? (k + 1) : (NT - 1);
#pragma unroll
            for (int j = 0; j < 4; ++j) upf[j] = fb[(size_t)kn * (fstep >> 2) + j];
        }

        // fixed-point iterations, warm start y_prev (already in LDS)
        f32x2 y = yp;
#pragma unroll
        for (int it = 0; it < FP_ITERS; ++it) {
            f32x2 z0 = fu, z1 = (f32x2){0.f, 0.f};
#pragma unroll
            for (int i = 0; i < 8; ++i) {
                f32x4 yv = ((const f32x4*)Yw)[i];   // broadcast within b-group
                z0 = W2[4*i+0] * yv[0] + z0;
                z1 = W2[4*i+1] * yv[1] + z1;
                z0 = W2[4*i+2] * yv[2] + z0;
                z1 = W2[4*i+3] * yv[3] + z1;
            }
            f32x2 t = tanh2(z0 + z1);
            y[0] = fmaf(DT, t[0], yp[0]);
            y[1] = fmaf(DT, t[1], yp[1]);
            // wave-lockstep: all reads above issued before this write; DS pipe
            // is in-order per wave; clobbers pin compiler ordering.
            asm volatile("" ::: "memory");
            *(f32x2*)(Yw + 2*p) = y;   // final write seeds next step's warm start
            asm volatile("" ::: "memory");
        }

        yp = y;
        *(f32x2*)(out + ((size_t)k * NB + batch) * NS + 2*p) = y;
    }
}

extern "C" void kernel_launch(void* const* d_in, const int* in_sizes, int n_in,
                              void* d_out, int out_size, void* d_ws, size_t ws_size,
                              hipStream_t stream) {
    const float* y0     = (const float*)d_in[0];
    const float* forces = (const float*)d_in[1];
    const float* W      = (const float*)d_in[2];
    const float* U      = (const float*)d_in[3];
    const float* b      = (const float*)d_in[4];
    float* out = (float*)d_out;

    dim3 grid(NB / 16);   // 512 blocks x 4 waves x 4 batches = 8192
    dim3 block(256);
    rnes_kernel<<<grid, block, 0, stream>>>(y0, forces, W, U, b, out);
}